// Round 5
// baseline (553.448 us; speedup 1.0000x reference)
//
#include <hip/hip_runtime.h>
#include <math.h>

#define B_   16
#define C_   128
#define W_   128
#define HW_  16384

typedef unsigned short ushort_t;
typedef unsigned int uint_t;
typedef short sh4 __attribute__((ext_vector_type(4)));
typedef short short8 __attribute__((ext_vector_type(8)));
typedef float f32x16 __attribute__((ext_vector_type(16)));

// workspace float offsets
#define OFF_GAP   0
#define OFF_FAVG  2048
#define OFF_CTX   4096
#define OFF_G     6144
#define OFF_CB    8192
#define OFF_WTS   10240
#define OFF_PMAX  10496
#define OFF_PSUM  12544
#define OFF_WHI   16384   /* ushort[16384] = 8192 floats */
#define OFF_WLO   24576   /* ushort[16384] = 8192 floats */
#define OFF_M     32768
#define OFF_SMAP  294912  /* NS * 262144 floats */

__device__ __forceinline__ float wave_reduce_sum(float v) {
#pragma unroll
  for (int o = 32; o > 0; o >>= 1) v += __shfl_xor(v, o, 64);
  return v;
}
__device__ __forceinline__ float wave_reduce_max(float v) {
#pragma unroll
  for (int o = 32; o > 0; o >>= 1) v = fmaxf(v, __shfl_xor(v, o, 64));
  return v;
}
__device__ __forceinline__ ushort_t rne_bf16(float f) {
  uint_t u = __float_as_uint(f);
  return (ushort_t)((u + 0x7FFFu + ((u >> 16) & 1u)) >> 16);
}
__device__ __forceinline__ float bf16_to_f(ushort_t h) {
  return __uint_as_float(((uint_t)h) << 16);
}

// ================= N1: fused k1 (gap/favg, inline sarr) + k2 (mask logits + partial stats)
// grid 4096: blocks [0,2048) -> k1 over (b,c) planes; [2048,4096) -> k2 over (b,128p chunks)
__global__ __launch_bounds__(256) void n1_stats(const float* __restrict__ x,
                                                const float* __restrict__ gcw,
                                                const float* __restrict__ gcb,
                                                float* __restrict__ gap,
                                                float* __restrict__ favg,
                                                float* __restrict__ m,
                                                float* __restrict__ pmax,
                                                float* __restrict__ psum) {
  int tid = threadIdx.x;
  if (blockIdx.x < 2048) {
    // ---- k1: per-(b,c) plane reductions ----
    __shared__ float sL[128];
    __shared__ float buf[8];
    int bc = blockIdx.x;
    if (tid < 128) {
      // sarr[n] = 1 + (-1)^n * cot(pi*(2n+1)/512)  (closed form of the DCT row-sum)
      float a2 = 0.006135923151542565f * (float)(2 * tid + 1);  // pi/512*(2n+1)
      float ct = __cosf(a2) / __sinf(a2);
      sL[tid] = 1.f + ((tid & 1) ? -ct : ct);
    }
    __syncthreads();
    const float* xp = x + (size_t)bc * HW_;
    float s0 = 0.f, s1 = 0.f;
    for (int i = tid << 2; i < HW_; i += 1024) {
      float4 v = *(const float4*)(xp + i);
      int y = i >> 7, xs = i & 127;
      float shy = sL[y];
      float d = v.x * sL[xs] + v.y * sL[xs + 1] + v.z * sL[xs + 2] + v.w * sL[xs + 3];
      s0 += v.x + v.y + v.z + v.w;
      s1 += shy * d;
    }
    s0 = wave_reduce_sum(s0);
    s1 = wave_reduce_sum(s1);
    int lane = tid & 63, wv = tid >> 6;
    if (lane == 0) { buf[wv] = s0; buf[4 + wv] = s1; }
    __syncthreads();
    if (tid == 0) {
      gap[bc]  = (buf[0] + buf[1] + buf[2] + buf[3]) * (1.f / 16384.f);
      favg[bc] = (buf[4] + buf[5] + buf[6] + buf[7]) * (1.f / 16384.f);
    }
  } else {
    // ---- k2: mask logits for 128 pixels + partial softmax stats ----
    __shared__ float macc[256];
    __shared__ float bmax[4], bsum[4];
    int blk = blockIdx.x - 2048;     // b*128 + pc
    int b = blk >> 7, pc = blk & 127;
    int p0 = pc << 7;
    int pl = tid & 127, chalf = tid >> 7;
    const float* xp = x + ((size_t)b * C_ + (size_t)chalf * 64) * HW_ + p0 + pl;
    const float* gw = gcw + chalf * 64;
    float acc = 0.f;
#pragma unroll 8
    for (int i = 0; i < 64; ++i) acc = fmaf(gw[i], xp[(size_t)i * HW_], acc);
    macc[tid] = acc;
    __syncthreads();
    float mval = 0.f;
    bool act = tid < 128;
    if (act) {
      mval = macc[tid] + macc[tid + 128] + gcb[0];
      m[(size_t)b * HW_ + p0 + tid] = mval;
    }
    float mx = act ? mval : -1e30f;
    mx = wave_reduce_max(mx);
    if ((tid & 63) == 0) bmax[tid >> 6] = mx;
    __syncthreads();
    float gmax = fmaxf(bmax[0], bmax[1]);
    float se = act ? __expf(mval - gmax) : 0.f;
    se = wave_reduce_sum(se);
    if ((tid & 63) == 0) bsum[tid >> 6] = se;
    __syncthreads();
    if (tid == 0) { pmax[blk] = gmax; psum[blk] = bsum[0] + bsum[1]; }
  }
}

// ================= N2: ctx[b,c] = sinv_b * sum_p x[b,c,p]*exp(m[b,p]-smx_b)
__global__ __launch_bounds__(256) void n2_ctx(const float* __restrict__ x,
                                              const float* __restrict__ m,
                                              const float* __restrict__ pmax,
                                              const float* __restrict__ psum,
                                              float* __restrict__ ctx) {
  __shared__ float sred[8];
  __shared__ float buf[4];
  __shared__ float sm_sh, si_sh;
  int tid = threadIdx.x;
  int bc = blockIdx.x;
  int b = bc >> 7;
  float pm = -1e30f, ps = 0.f;
  if (tid < 128) { pm = pmax[(b << 7) + tid]; ps = psum[(b << 7) + tid]; }
  float gm = wave_reduce_max(pm);
  if ((tid & 63) == 0) sred[tid >> 6] = gm;
  __syncthreads();
  gm = fmaxf(sred[0], sred[1]);
  float e = (tid < 128) ? ps * __expf(pm - gm) : 0.f;
  e = wave_reduce_sum(e);
  if ((tid & 63) == 0) sred[4 + (tid >> 6)] = e;
  __syncthreads();
  if (tid == 0) { sm_sh = gm; si_sh = 1.f / (sred[4] + sred[5]); }
  __syncthreads();
  float smx = sm_sh, sinv = si_sh;
  const float* xp = x + (size_t)bc * HW_;
  const float* mp = m + (size_t)b * HW_;
  float s = 0.f;
  for (int i = tid << 2; i < HW_; i += 1024) {
    float4 v = *(const float4*)(xp + i);
    float4 mv = *(const float4*)(mp + i);
    s += v.x * __expf(mv.x - smx) + v.y * __expf(mv.y - smx) +
         v.z * __expf(mv.z - smx) + v.w * __expf(mv.w - smx);
  }
  s = wave_reduce_sum(s);
  if ((tid & 63) == 0) buf[tid >> 6] = s;
  __syncthreads();
  if (tid == 0) ctx[bc] = (buf[0] + buf[1] + buf[2] + buf[3]) * sinv;
}

// ================= N3: blocks 0-15: tiny MLPs + fusion scalars; blocks 16-31: W hi/lo bf16 split
__global__ __launch_bounds__(128) void n3_mlp(
    const float* __restrict__ gap, const float* __restrict__ favg,
    const float* __restrict__ ctx,
    const float* __restrict__ ca_w1, const float* __restrict__ ca_b1,
    const float* __restrict__ ca_w2, const float* __restrict__ ca_b2,
    const float* __restrict__ fa_w1, const float* __restrict__ fa_b1,
    const float* __restrict__ fa_w2, const float* __restrict__ fa_b2,
    const float* __restrict__ t1w, const float* __restrict__ t1b,
    const float* __restrict__ lng, const float* __restrict__ lnb,
    const float* __restrict__ t2w, const float* __restrict__ t2b,
    const float* __restrict__ alpha,
    const float* __restrict__ out_w, const float* __restrict__ out_b,
    float* __restrict__ g, float* __restrict__ cb, float* __restrict__ wts,
    ushort_t* __restrict__ whi, ushort_t* __restrict__ wlo) {
  int t = threadIdx.x;
  if (blockIdx.x >= 16) {
    int base = (blockIdx.x - 16) * 1024 + t;
#pragma unroll
    for (int k = 0; k < 8; ++k) {
      int idx = base + k * 128;
      float w = out_w[idx];
      ushort_t h = rne_bf16(w);
      whi[idx] = h;
      wlo[idx] = rne_bf16(w - bf16_to_f(h));
    }
    return;
  }
  int b = blockIdx.x;
  __shared__ float gapL[128], favL[128], ctxL[128], hca[16], hfa[16], tl[8], dl[128];
  gapL[t] = gap[(b << 7) + t];
  favL[t] = favg[(b << 7) + t];
  ctxL[t] = ctx[(b << 7) + t];
  __syncthreads();
  if (t < 16) {
    float a = ca_b1[t], f = fa_b1[t];
    for (int c = 0; c < 128; ++c) {
      a += gapL[c] * ca_w1[t * 128 + c];
      f += favL[c] * fa_w1[t * 128 + c];
    }
    hca[t] = fmaxf(a, 0.f);
    hfa[t] = fmaxf(f, 0.f);
  }
  if (t < 8) {
    float v = t1b[t];
    for (int c = 0; c < 128; ++c) v += ctxL[c] * t1w[t * 128 + c];
    tl[t] = v;
  }
  __syncthreads();
  float mu = 0.f;
#pragma unroll
  for (int j = 0; j < 8; ++j) mu += tl[j];
  mu *= 0.125f;
  float var = 0.f;
#pragma unroll
  for (int j = 0; j < 8; ++j) { float d = tl[j] - mu; var += d * d; }
  var *= 0.125f;
  float rs = rsqrtf(var + 1e-5f);
  float a0 = alpha[0], a1 = alpha[1], a2 = alpha[2], a3 = alpha[3];
  float am = fmaxf(fmaxf(a0, a1), fmaxf(a2, a3));
  float e0 = __expf(a0 - am), e1 = __expf(a1 - am), e2 = __expf(a2 - am), e3 = __expf(a3 - am);
  float es = 1.f / (e0 + e1 + e2 + e3);
  float w0 = e0 * es, w1 = e1 * es, w2 = e2 * es, w3 = e3 * es;
  float cav = ca_b2[t], fav = fa_b2[t], c2 = t2b[t];
#pragma unroll
  for (int j = 0; j < 16; ++j) {
    cav += hca[j] * ca_w2[t * 16 + j];
    fav += hfa[j] * fa_w2[t * 16 + j];
  }
#pragma unroll
  for (int j = 0; j < 8; ++j) {
    float tn = fmaxf((tl[j] - mu) * rs * lng[j] + lnb[j], 0.f);
    c2 += tn * t2w[t * 8 + j];
  }
  cav = 1.f / (1.f + __expf(-cav));
  fav = 1.f / (1.f + __expf(-fav));
  g[(b << 7) + t] = w0 * cav + w2 * fav + w3;
  dl[t] = w3 * c2;
  __syncthreads();
  float s = out_b[t];
  for (int c = 0; c < 128; ++c) s += out_w[t * 128 + c] * dl[c];
  cb[(b << 7) + t] = s;
  if (b == 0 && t < 4) wts[t] = (t == 0) ? w0 : (t == 1) ? w1 : (t == 2) ? w2 : w3;
}

// ================= N4: 9x9 conv partials, register-prefetch staged LDS
template <int CPS>
__global__ __launch_bounds__(256) void n4_conv(const float* __restrict__ x,
                                               const float* __restrict__ saw,
                                               float* __restrict__ smap_part) {
  __shared__ float tile[40 * 136];
  int tid = threadIdx.x;
  int yt = blockIdx.x;
  int b = blockIdx.y;
  int split = blockIdx.z;
  int y0 = yt << 5;
  int rg = tid >> 5;
  int cg = tid & 31;
  int r0 = rg << 2;
  int px0 = cg << 2;
  float acc[4][4];
#pragma unroll
  for (int i = 0; i < 4; ++i)
#pragma unroll
    for (int j = 0; j < 4; ++j) acc[i][j] = 0.f;
  const float* xb = x + (size_t)b * C_ * HW_;
  int c_lo = split * CPS;

  float4 pre[6];
  auto issue_loads = [&](int c) {
    const float* xc = xb + (size_t)c * HW_;
#pragma unroll
    for (int k = 0; k < 6; ++k) {
      int idx = tid + (k << 8);
      if (idx < 1360) {
        int row = idx / 34, c4 = idx - row * 34;
        int gy = y0 - 4 + row;
        int gx = (c4 << 2) - 4;
        float4 v = make_float4(0.f, 0.f, 0.f, 0.f);
        if (gy >= 0 && gy < 128 && gx >= 0 && gx <= 124)
          v = *(const float4*)(xc + gy * W_ + gx);
        pre[k] = v;
      }
    }
  };
  auto write_tile = [&]() {
#pragma unroll
    for (int k = 0; k < 6; ++k) {
      int idx = tid + (k << 8);
      if (idx < 1360) {
        int row = idx / 34, c4 = idx - row * 34;
        *(float4*)(tile + row * 136 + (c4 << 2)) = pre[k];
      }
    }
  };

  issue_loads(c_lo);
  for (int ci = 0; ci < CPS; ++ci) {
    __syncthreads();          // prior compute done, LDS free
    write_tile();
    __syncthreads();          // tile visible
    if (ci + 1 < CPS) issue_loads(c_lo + ci + 1);   // in flight under compute
    const float* wrow = saw + (c_lo + ci) * 81;
#pragma unroll
    for (int ir = 0; ir < 12; ++ir) {
      const float* tp = tile + (r0 + ir) * 136 + px0;
      float4 u0 = *(const float4*)tp;
      float4 u1 = *(const float4*)(tp + 4);
      float4 u2 = *(const float4*)(tp + 8);
      float rowv[12] = {u0.x, u0.y, u0.z, u0.w, u1.x, u1.y, u1.z, u1.w,
                        u2.x, u2.y, u2.z, u2.w};
#pragma unroll
      for (int i = 0; i < 4; ++i) {
        int dy = ir - i;
        if (dy < 0 || dy > 8) continue;
#pragma unroll
        for (int dx = 0; dx < 9; ++dx) {
          float wv = wrow[dy * 9 + dx];
#pragma unroll
          for (int j = 0; j < 4; ++j)
            acc[i][j] = fmaf(wv, rowv[dx + j], acc[i][j]);
        }
      }
    }
  }
  float* op = smap_part + ((size_t)(split * B_ + b)) * HW_ + (y0 + r0) * W_ + px0;
#pragma unroll
  for (int i = 0; i < 4; ++i)
    *(float4*)(op + (size_t)i * W_) = make_float4(acc[i][0], acc[i][1], acc[i][2], acc[i][3]);
}

// ================= N5: MFMA GEMM: out[b,o,p] = sum_c W[o,c]*x[b,c,p]*(g[c]+s[p]) + cb[b,o]
// A=W (bf16 hi/lo from global), B=xm (fp32 LDS -> bf16 hi/lo frags). 3-term split product.
// k-slot map kappa(j,h) = (j&3)+8*(j>>2)+4*h applied to BOTH operands (any bijection valid).
__global__ __launch_bounds__(256) void n5_gemm(const float* __restrict__ x,
                                               const ushort_t* __restrict__ whi,
                                               const ushort_t* __restrict__ wlo,
                                               const float* __restrict__ g,
                                               const float* __restrict__ smap,
                                               const float* __restrict__ wts,
                                               const float* __restrict__ sab,
                                               const float* __restrict__ cb,
                                               float* __restrict__ out,
                                               int ns) {
  __shared__ float xm[64 * 132];
  __shared__ float s_lds[128], g_lds[128], cb_lds[128];
  int tid = threadIdx.x;
  int b = blockIdx.x >> 7;
  int pt = blockIdx.x & 127;
  int p0 = pt << 7;

  if (tid < 128) {
    float a = sab[0];
    const float* sp = smap + (size_t)b * HW_ + p0 + tid;
    for (int j = 0; j < ns; ++j) a += sp[(size_t)j * (B_ * HW_)];
    s_lds[tid] = wts[1] / (1.f + __expf(-a));
  } else {
    int t2 = tid - 128;
    g_lds[t2] = g[(b << 7) + t2];
    cb_lds[t2] = cb[(b << 7) + t2];
  }

  int l = tid & 63;
  int w = tid >> 6;
  int wr = w >> 1, wc = w & 1;
  int h = l >> 5;
  int ln31 = l & 31;
  int c_l = tid >> 2, pq = tid & 3;

  f32x16 acc00, acc01, acc10, acc11;
#pragma unroll
  for (int j = 0; j < 16; ++j) { acc00[j] = 0.f; acc01[j] = 0.f; acc10[j] = 0.f; acc11[j] = 0.f; }

  for (int chunk = 0; chunk < 2; ++chunk) {
    __syncthreads();
    // ---- stage xm = x*(g+s) fp32 into LDS [64][132] ----
    float gc = g_lds[(chunk << 6) + c_l];
    const float* xg = x + ((size_t)b * C_ + (chunk << 6) + c_l) * HW_ + p0 + (pq << 5);
    float* wl = xm + c_l * 132 + (pq << 5);
#pragma unroll
    for (int i = 0; i < 8; ++i) {
      float4 v = *(const float4*)(xg + (i << 2));
      float4 sv = *(const float4*)(s_lds + (pq << 5) + (i << 2));
      float4 r;
      r.x = v.x * (gc + sv.x);
      r.y = v.y * (gc + sv.y);
      r.z = v.z * (gc + sv.z);
      r.w = v.w * (gc + sv.w);
      *(float4*)(wl + (i << 2)) = r;
    }
    __syncthreads();
#pragma unroll
    for (int ks = 0; ks < 4; ++ks) {
      int cb16 = ks << 4;
      // A fragments (global bf16, L1/L2-hot): slots j0-3 = c0+0..3, j4-7 = c0+8+0..3
      short8 ahi0, ahi1, alo0, alo1;
      {
        int cg0 = (chunk << 6) + cb16 + (h << 2);
        const ushort_t* wp0 = whi + ((wr << 6) + ln31) * 128 + cg0;
        const ushort_t* wp1 = whi + ((wr << 6) + 32 + ln31) * 128 + cg0;
        const ushort_t* vp0 = wlo + ((wr << 6) + ln31) * 128 + cg0;
        const ushort_t* vp1 = wlo + ((wr << 6) + 32 + ln31) * 128 + cg0;
        sh4 a0 = *(const sh4*)(const void*)wp0, a1 = *(const sh4*)(const void*)(wp0 + 8);
        ahi0 = __builtin_shufflevector(a0, a1, 0, 1, 2, 3, 4, 5, 6, 7);
        sh4 b0 = *(const sh4*)(const void*)wp1, b1 = *(const sh4*)(const void*)(wp1 + 8);
        ahi1 = __builtin_shufflevector(b0, b1, 0, 1, 2, 3, 4, 5, 6, 7);
        sh4 c0 = *(const sh4*)(const void*)vp0, c1 = *(const sh4*)(const void*)(vp0 + 8);
        alo0 = __builtin_shufflevector(c0, c1, 0, 1, 2, 3, 4, 5, 6, 7);
        sh4 d0 = *(const sh4*)(const void*)vp1, d1 = *(const sh4*)(const void*)(vp1 + 8);
        alo1 = __builtin_shufflevector(d0, d1, 0, 1, 2, 3, 4, 5, 6, 7);
      }
      // B fragments per p-tile: 8 conflict-free b32 LDS reads + hi/lo split
#pragma unroll
      for (int ptile = 0; ptile < 2; ++ptile) {
        int pcol = (wc << 6) + (ptile << 5) + ln31;
        short8 bhi, blo;
#pragma unroll
        for (int j = 0; j < 8; ++j) {
          int co = (j & 3) + ((j >> 2) << 3) + (h << 2);  // kappa(j,h)
          float f = xm[(cb16 + co) * 132 + pcol];
          uint_t u = __float_as_uint(f);
          uint_t hu = (u + 0x7FFFu + ((u >> 16) & 1u)) >> 16;
          float lof = f - __uint_as_float(hu << 16);
          uint_t ul = __float_as_uint(lof);
          uint_t lu = (ul + 0x7FFFu + ((ul >> 16) & 1u)) >> 16;
          bhi[j] = (short)hu;
          blo[j] = (short)lu;
        }
        if (ptile == 0) {
          acc00 = __builtin_amdgcn_mfma_f32_32x32x16_bf16(ahi0, bhi, acc00, 0, 0, 0);
          acc00 = __builtin_amdgcn_mfma_f32_32x32x16_bf16(ahi0, blo, acc00, 0, 0, 0);
          acc00 = __builtin_amdgcn_mfma_f32_32x32x16_bf16(alo0, bhi, acc00, 0, 0, 0);
          acc10 = __builtin_amdgcn_mfma_f32_32x32x16_bf16(ahi1, bhi, acc10, 0, 0, 0);
          acc10 = __builtin_amdgcn_mfma_f32_32x32x16_bf16(ahi1, blo, acc10, 0, 0, 0);
          acc10 = __builtin_amdgcn_mfma_f32_32x32x16_bf16(alo1, bhi, acc10, 0, 0, 0);
        } else {
          acc01 = __builtin_amdgcn_mfma_f32_32x32x16_bf16(ahi0, bhi, acc01, 0, 0, 0);
          acc01 = __builtin_amdgcn_mfma_f32_32x32x16_bf16(ahi0, blo, acc01, 0, 0, 0);
          acc01 = __builtin_amdgcn_mfma_f32_32x32x16_bf16(alo0, bhi, acc01, 0, 0, 0);
          acc11 = __builtin_amdgcn_mfma_f32_32x32x16_bf16(ahi1, bhi, acc11, 0, 0, 0);
          acc11 = __builtin_amdgcn_mfma_f32_32x32x16_bf16(ahi1, blo, acc11, 0, 0, 0);
          acc11 = __builtin_amdgcn_mfma_f32_32x32x16_bf16(alo1, bhi, acc11, 0, 0, 0);
        }
      }
    }
  }
  // ---- store: C/D map row=(reg&3)+8*(reg>>2)+4*h (HW-verified), col=ln31 ----
  size_t ob = (size_t)(b << 7) * HW_ + p0;
#define STORE_FRAG(ACC, OT, PT)                                                  \
  {                                                                              \
    int obase = (wr << 6) + ((OT) << 5);                                         \
    int pp = (wc << 6) + ((PT) << 5) + ln31;                                     \
    _Pragma("unroll") for (int reg = 0; reg < 16; ++reg) {                       \
      int o = obase + (reg & 3) + ((reg >> 2) << 3) + (h << 2);                  \
      out[ob + (size_t)o * HW_ + pp] = (ACC)[reg] + cb_lds[o];                   \
    }                                                                            \
  }
  STORE_FRAG(acc00, 0, 0)
  STORE_FRAG(acc10, 1, 0)
  STORE_FRAG(acc01, 0, 1)
  STORE_FRAG(acc11, 1, 1)
#undef STORE_FRAG
}

extern "C" void kernel_launch(void* const* d_in, const int* in_sizes, int n_in,
                              void* d_out, int out_size, void* d_ws, size_t ws_size,
                              hipStream_t stream) {
  const float* x       = (const float*)d_in[0];
  const float* ca_w1   = (const float*)d_in[1];
  const float* ca_b1   = (const float*)d_in[2];
  const float* ca_w2   = (const float*)d_in[3];
  const float* ca_b2   = (const float*)d_in[4];
  const float* sa_w    = (const float*)d_in[5];
  const float* sa_b    = (const float*)d_in[6];
  const float* fa_w1   = (const float*)d_in[7];
  const float* fa_b1   = (const float*)d_in[8];
  const float* fa_w2   = (const float*)d_in[9];
  const float* fa_b2   = (const float*)d_in[10];
  const float* gc_mw   = (const float*)d_in[11];
  const float* gc_mb   = (const float*)d_in[12];
  const float* gc_t1w  = (const float*)d_in[13];
  const float* gc_t1b  = (const float*)d_in[14];
  const float* gc_lng  = (const float*)d_in[15];
  const float* gc_lnb  = (const float*)d_in[16];
  const float* gc_t2w  = (const float*)d_in[17];
  const float* gc_t2b  = (const float*)d_in[18];
  const float* alpha   = (const float*)d_in[19];
  const float* out_w   = (const float*)d_in[20];
  const float* out_b   = (const float*)d_in[21];
  float* out = (float*)d_out;
  float* ws = (float*)d_ws;

  float* gap  = ws + OFF_GAP;
  float* favg = ws + OFF_FAVG;
  float* ctx  = ws + OFF_CTX;
  float* g    = ws + OFF_G;
  float* cb   = ws + OFF_CB;
  float* wts  = ws + OFF_WTS;
  float* pmax = ws + OFF_PMAX;
  float* psum = ws + OFF_PSUM;
  ushort_t* whi = (ushort_t*)(ws + OFF_WHI);
  ushort_t* wlo = (ushort_t*)(ws + OFF_WLO);
  float* m    = ws + OFF_M;
  float* smap = ws + OFF_SMAP;

  auto need = [](int ns) { return (size_t)(OFF_SMAP + (size_t)ns * 262144) * sizeof(float); };

  n1_stats<<<4096, 256, 0, stream>>>(x, gc_mw, gc_mb, gap, favg, m, pmax, psum);
  n2_ctx<<<2048, 256, 0, stream>>>(x, m, pmax, psum, ctx);
  n3_mlp<<<32, 128, 0, stream>>>(gap, favg, ctx, ca_w1, ca_b1, ca_w2, ca_b2,
                                 fa_w1, fa_b1, fa_w2, fa_b2, gc_t1w, gc_t1b,
                                 gc_lng, gc_lnb, gc_t2w, gc_t2b, alpha,
                                 out_w, out_b, g, cb, wts, whi, wlo);
  int ns;
  if (ws_size >= need(32)) {
    ns = 32; n4_conv<4><<<dim3(4, 16, 32), 256, 0, stream>>>(x, sa_w, smap);
  } else if (ws_size >= need(16)) {
    ns = 16; n4_conv<8><<<dim3(4, 16, 16), 256, 0, stream>>>(x, sa_w, smap);
  } else if (ws_size >= need(8)) {
    ns = 8; n4_conv<16><<<dim3(4, 16, 8), 256, 0, stream>>>(x, sa_w, smap);
  } else {
    ns = 4; n4_conv<32><<<dim3(4, 16, 4), 256, 0, stream>>>(x, sa_w, smap);
  }
  n5_gemm<<<2048, 256, 0, stream>>>(x, whi, wlo, g, smap, wts, sa_b, cb, out, ns);
}